// Round 2
// baseline (1452.143 us; speedup 1.0000x reference)
//
#include <hip/hip_runtime.h>

// bf16 MFMA fragment types per cdna_hip_programming.md §3
typedef short short8 __attribute__((ext_vector_type(8)));   // 8 bf16 (4 VGPRs)
typedef float f32x4 __attribute__((ext_vector_type(4)));    // 4 fp32 acc
typedef unsigned int uint4v __attribute__((ext_vector_type(4)));

static constexpr int kH = 128;   // hidden dim (z rows are 128 fp32 = 512 B)

// fp32 -> bf16 round-to-nearest-even, manual (no HIP class types: bit_cast-safe)
__device__ __forceinline__ unsigned f2bf(float f) {
    unsigned u = __builtin_bit_cast(unsigned, f);
    u += 0x7fffu + ((u >> 16) & 1u);
    return u >> 16;
}
__device__ __forceinline__ unsigned pack_bf16x2(float a, float b) {
    return f2bf(a) | (f2bf(b) << 16);   // a in low 16 (element 0)
}

struct U128 { unsigned x, y, z, w; };

// Block = 256 threads = 4 waves. LDS = 64 KiB (W1 in MFMA-B fragment order)
// -> 2 blocks/CU (LDS-capped), so allow up to 256 VGPRs.
__global__ __launch_bounds__(256, 2) void edge_mlp(
    const float* __restrict__ zc, const float* __restrict__ za,
    const int* __restrict__ row, const int* __restrict__ col,
    const float* __restrict__ W1, const float* __restrict__ b1,
    const float* __restrict__ W2, const float* __restrict__ b2,
    float* __restrict__ out, int E, int ntiles)
{
    // W1 bf16, fragment-ordered: short index ((s*8+nt)*64 + lane)*8 + j
    //   = B[n = nt*16 + (lane&15)][k = s*32 + (lane>>4)*8 + j]
    // Stored as uints (2 bf16 each): lane-contiguous 16B chunks -> conflict-free ds_read_b128.
    __shared__ unsigned ldsB[16384];  // 64 KiB

    const int tid = threadIdx.x;

    // ---- one-time LDS fill (per block; amortized over grid-stride tiles) ----
    #pragma unroll 4
    for (int i = 0; i < 64; ++i) {
        int lin2 = tid + i * 256;          // uint index
        int j  = (lin2 & 3) * 2;           // bf16 element (even)
        int l  = (lin2 >> 2) & 63;
        int nt = (lin2 >> 8) & 7;
        int s  = (lin2 >> 11) & 7;
        int q = l >> 4, n = l & 15;
        int k = s * 32 + q * 8 + j;
        int ncol = nt * 16 + n;
        float f0 = W1[k * kH + ncol];
        float f1 = W1[(k + 1) * kH + ncol];
        ldsB[lin2] = pack_bf16x2(f0, f1);
    }
    __syncthreads();   // only barrier in the kernel; waves run free afterwards

    const int w   = tid >> 6;   // wave 0..3
    const int l   = tid & 63;
    const int q   = l >> 4;     // quad (k-chunk / C-row group)
    const int n16 = l & 15;     // A-row (edge) / C-col (output n)

    // Per-lane epilogue constants: b1/W2 at this lane's output column per n-tile.
    float b1v[8], w2v[8];
    #pragma unroll
    for (int nt = 0; nt < 8; ++nt) {
        b1v[nt] = b1[nt * 16 + n16];
        w2v[nt] = W2[nt * 16 + n16];
    }
    const float b2s = b2[0];

    // Each wave: 32 edges per tile-iter (2 M-tiles of 16). Block: 128 edges.
    for (int tile = blockIdx.x; tile < ntiles; tile += gridDim.x) {
        const int ebase = tile * 128 + w * 32;
        int e0 = ebase + n16;
        int e1 = ebase + 16 + n16;
        int ce0 = min(e0, E - 1);
        int ce1 = min(e1, E - 1);
        const float* pc0 = zc + (size_t)row[ce0] * kH;
        const float* pa0 = za + (size_t)col[ce0] * kH;
        const float* pc1 = zc + (size_t)row[ce1] * kH;
        const float* pa1 = za + (size_t)col[ce1] * kH;

        f32x4 acc[2][8];
        #pragma unroll
        for (int mt = 0; mt < 2; ++mt)
            #pragma unroll
            for (int nt = 0; nt < 8; ++nt)
                acc[mt][nt] = f32x4{0.f, 0.f, 0.f, 0.f};

        #pragma unroll
        for (int s = 0; s < 8; ++s) {
            // k = s*32 + q*8 + (0..7); first 128 k from customer, last 128 from article
            const float* s0 = (s < 4) ? (pc0 + s * 32) : (pa0 + (s - 4) * 32);
            const float* s1 = (s < 4) ? (pc1 + s * 32) : (pa1 + (s - 4) * 32);
            float4 fa = *(const float4*)(s0 + q * 8);
            float4 fb = *(const float4*)(s0 + q * 8 + 4);
            float4 fc = *(const float4*)(s1 + q * 8);
            float4 fd = *(const float4*)(s1 + q * 8 + 4);
            U128 ua{pack_bf16x2(fa.x, fa.y), pack_bf16x2(fa.z, fa.w),
                    pack_bf16x2(fb.x, fb.y), pack_bf16x2(fb.z, fb.w)};
            U128 ub{pack_bf16x2(fc.x, fc.y), pack_bf16x2(fc.z, fc.w),
                    pack_bf16x2(fd.x, fd.y), pack_bf16x2(fd.z, fd.w)};
            short8 a0 = __builtin_bit_cast(short8, ua);
            short8 a1 = __builtin_bit_cast(short8, ub);
            #pragma unroll
            for (int nt = 0; nt < 8; ++nt) {
                uint4v bu = *(const uint4v*)(&ldsB[((s * 8 + nt) * 64 + l) * 4]);
                short8 bv = __builtin_bit_cast(short8, bu);
                acc[0][nt] = __builtin_amdgcn_mfma_f32_16x16x32_bf16(a0, bv, acc[0][nt], 0, 0, 0);
                acc[1][nt] = __builtin_amdgcn_mfma_f32_16x16x32_bf16(a1, bv, acc[1][nt], 0, 0, 0);
            }
        }

        // ---- epilogue: h = relu(acc + b1); out = h . W2 + b2 ----
        // C layout: col = lane&15 (output n within tile), row = q*4 + reg (edge within M-tile)
        #pragma unroll
        for (int mt = 0; mt < 2; ++mt) {
            float p[4];
            #pragma unroll
            for (int r = 0; r < 4; ++r) {
                float sum = 0.f;
                #pragma unroll
                for (int nt = 0; nt < 8; ++nt)
                    sum += fmaxf(acc[mt][nt][r] + b1v[nt], 0.f) * w2v[nt];
                // reduce over the 16 output-columns held by lanes sharing q
                sum += __shfl_xor(sum, 1);
                sum += __shfl_xor(sum, 2);
                sum += __shfl_xor(sum, 4);
                sum += __shfl_xor(sum, 8);
                p[r] = sum + b2s;
            }
            if (n16 == 0) {
                int eb = ebase + mt * 16 + q * 4;   // 4 consecutive edges
                if (eb + 3 < E) {
                    *(float4*)(out + eb) = make_float4(p[0], p[1], p[2], p[3]);
                } else {
                    #pragma unroll
                    for (int r = 0; r < 4; ++r)
                        if (eb + r < E) out[eb + r] = p[r];
                }
            }
        }
    }
}

extern "C" void kernel_launch(void* const* d_in, const int* in_sizes, int n_in,
                              void* d_out, int out_size, void* d_ws, size_t ws_size,
                              hipStream_t stream) {
    const float* zc = (const float*)d_in[0];   // [N_CUST, 128] fp32
    const float* za = (const float*)d_in[1];   // [N_ART, 128] fp32
    const int*   row = (const int*)d_in[2];    // [E] int32
    const int*   col = (const int*)d_in[3];    // [E] int32
    const float* W1 = (const float*)d_in[4];   // [256, 128] fp32 row-major
    const float* b1 = (const float*)d_in[5];   // [128]
    const float* W2 = (const float*)d_in[6];   // [128, 1]
    const float* b2 = (const float*)d_in[7];   // [1]
    float* out = (float*)d_out;                // [E] fp32

    int E = in_sizes[2];
    int ntiles = (E + 127) / 128;
    int grid = ntiles < 1024 ? ntiles : 1024;
    edge_mlp<<<grid, 256, 0, stream>>>(zc, za, row, col, W1, b1, W2, b2, out, E, ntiles);
}